// Round 18
// baseline (131.349 us; speedup 1.0000x reference)
//
#include <hip/hip_runtime.h>

#define QPB    4           // queries per block: each loaded point is tested
                           // against 4 filters -> xyz bytes through the L1
                           // port drop 4x (phase-1 is L1-BW-bound, see R18)
#define CAP    4544        // per-query loose capacity (exact <= 4096 verified,
                           // loose margin ~+3% -> ~4220). Overflow -> identity
                           // -scan fallback (correct, just slower). 4*CAP
                           // ushort = 35.5 KB -> 4 blocks/CU.
#define BIGK   1.0e300
#define IDXINF 0x7fffffff

// one bitonic compare-exchange stage across the 64-lane wave,
// lexicographic key (k asc, n asc)
__device__ __forceinline__ void cmpx(double& k, int& n, int lane, int stride, bool up) {
    double ok = __shfl_xor(k, stride);
    int    on = __shfl_xor(n, stride);
    bool oLess = (ok < k) || (ok == k && on < n);
    bool lower = (lane & stride) == 0;
    bool takeOther = lower ? (up ? oLess : !oLess) : (up ? !oLess : oLess);
    if (takeOther) { k = ok; n = on; }
}

// full 64-element bitonic sort across the wave (asc==true -> ascending)
__device__ __forceinline__ void wave_sort64(double& k, int& n, int lane, bool asc) {
    #pragma unroll
    for (int size = 2; size < 64; size <<= 1) {
        bool up = asc ? ((lane & size) == 0) : ((lane & size) != 0);
        #pragma unroll
        for (int stride = size >> 1; stride > 0; stride >>= 1)
            cmpx(k, n, lane, stride, up);
    }
    #pragma unroll
    for (int stride = 32; stride > 0; stride >>= 1)   // final size-64 pass
        cmpx(k, n, lane, stride, asc);
}

// ---- Kernel 1: 4-query selection + grouped_xyz; sel -> d_ws (ushort) ----
__global__ __launch_bounds__(256, 4) void select_kernel(
    const float* __restrict__ radius_p,
    const float* __restrict__ hmin_p,
    const float* __restrict__ hmax_p,
    const float* __restrict__ xyz,      // (B, N, 3)
    const float* __restrict__ new_xyz,  // (B, P, 3)
    const float* __restrict__ rot,      // (B, P, 3, 3)
    float* __restrict__ out,            // (B, 3+C, P, S)
    unsigned short* __restrict__ selw)  // (B*P, 32)
{
    const int N = 16384, P = 1024, S = 32, OC = 67;
    const int bid = blockIdx.x;         // 1024 blocks
    const int b   = bid >> 8;           // 256 blocks per batch
    const int p0  = (bid & 255) * QPB;  // first query p of this block
    const int tid = threadIdx.x;
    const int lane = tid & 63;
    const int wv   = tid >> 6;

    __shared__ unsigned short cn[QPB][CAP];  // 35.5 KB loose candidates
    __shared__ double wr2[256];              // per-wave keys for the merge
    __shared__ int    wn[256];
    __shared__ int    cnt[QPB];
    __shared__ int    cnt2[QPB];
    __shared__ int    sel[32];

    if (tid < QPB) { cnt[tid] = 0; cnt2[tid] = 0; }
    __syncthreads();

    const double hmin = (double)hmin_p[0];
    const double hmax = (double)hmax_p[0];
    const double rad  = (double)radius_p[0];
    const double rad2 = rad * rad;
    const float hminf = (float)hmin - 5.0e-4f;   // margins: f32 err ~1e-5,
    const float hmaxf = (float)hmax + 5.0e-4f;   // 50-100x cushion (R10-R17)
    const float rad2f = (float)rad2 + 1.0e-3f;

    // per-query projection-form f32 filter consts (block-uniform -> SGPRs).
    // cp_d computed in f64 then cast (same formula as verified R14-R17).
    float R00[QPB], R01[QPB], R02[QPB], R10[QPB], R11[QPB], R12[QPB],
          R20[QPB], R21[QPB], R22[QPB], CPX[QPB], CPY[QPB], CPZ[QPB];
    #pragma unroll
    for (int q = 0; q < QPB; ++q) {
        const float* rp = rot     + ((size_t)(b * P + p0 + q)) * 9;
        const float* nx = new_xyz + ((size_t)(b * P + p0 + q)) * 3;
        double r00 = rp[0], r01 = rp[1], r02 = rp[2];
        double r10 = rp[3], r11 = rp[4], r12 = rp[5];
        double r20 = rp[6], r21 = rp[7], r22 = rp[8];
        double cx = nx[0], cy = nx[1], cz = nx[2];
        R00[q] = (float)r00; R01[q] = (float)r01; R02[q] = (float)r02;
        R10[q] = (float)r10; R11[q] = (float)r11; R12[q] = (float)r12;
        R20[q] = (float)r20; R21[q] = (float)r21; R22[q] = (float)r22;
        CPX[q] = (float)(cx * r00 + cy * r10 + cz * r20);
        CPY[q] = (float)(cx * r01 + cy * r11 + cz * r21);
        CPZ[q] = (float)(cx * r02 + cy * r12 + cz * r22);
    }

    const float* xb = xyz + (size_t)b * N * 3;
    const float4* vp = reinterpret_cast<const float4*>(xb);

    // ---- Phase 1: pure-f32 loose scan; each point tested vs 4 queries ----
    float4 a0 = vp[tid * 3 + 0], a1 = vp[tid * 3 + 1], a2 = vp[tid * 3 + 2];
    for (int it = 0; it < 16; ++it) {               // 16 * 1024 = N
        const float4* qv = vp + ((it + 1) & 15) * 768 + tid * 3;
        float4 b0 = qv[0], b1 = qv[1], b2 = qv[2];  // prefetch (issue-early)
        int g = it * 1024 + tid * 4;
        float px[4], py[4], pz[4];
        px[0]=a0.x; py[0]=a0.y; pz[0]=a0.z;
        px[1]=a0.w; py[1]=a1.x; pz[1]=a1.y;
        px[2]=a1.z; py[2]=a1.w; pz[2]=a2.x;
        px[3]=a2.y; py[3]=a2.z; pz[3]=a2.w;
        #pragma unroll
        for (int k = 0; k < 4; ++k) {
            #pragma unroll
            for (int q = 0; q < QPB; ++q) {
                float xf  = fmaf(px[k], R00[q], fmaf(py[k], R10[q], fmaf(pz[k], R20[q], -CPX[q])));
                float yf  = fmaf(px[k], R01[q], fmaf(py[k], R11[q], fmaf(pz[k], R21[q], -CPY[q])));
                float zf  = fmaf(px[k], R02[q], fmaf(py[k], R12[q], fmaf(pz[k], R22[q], -CPZ[q])));
                float r2f = fmaf(yf, yf, zf * zf);
                if (xf >= hminf && xf <= hmaxf && r2f < rad2f) {
                    int slot = atomicAdd(&cnt[q], 1);   // compiler wave-coalesces
                    if (slot < CAP) cn[q][slot] = (unsigned short)(g + k);
                }
            }
        }
        a0 = b0; a1 = b1; a2 = b2;
    }
    __syncthreads();

    // ---- Phase 2 (per query, sequential): exact f64 decision fused into
    //      chunk load + streaming bitonic top-64/wave + 4-way merge ----
    #pragma unroll 1
    for (int q = 0; q < QPB; ++q) {
        const int bp = b * P + p0 + q;
        const int p  = p0 + q;
        const float* rp = rot     + (size_t)bp * 9;
        const float* nx = new_xyz + (size_t)bp * 3;
        const double r00 = rp[0], r01 = rp[1], r02 = rp[2];
        const double r10 = rp[3], r11 = rp[4], r12 = rp[5];
        const double r20 = rp[6], r21 = rp[7], r22 = rp[8];
        const double cx = nx[0], cy = nx[1], cz = nx[2];

        int  Mloose = cnt[q];
        bool ident  = false;
        if (Mloose > CAP) { Mloose = N; ident = true; }  // overflow-proof

        double rk = BIGK; int rn = IDXINF;
        int msum = 0;
        const int nch = (Mloose + 63) >> 6;
        for (int ch = wv; ch < nch; ch += 4) {
            int j = (ch << 6) + lane;
            double ck = BIGK; int cnn = IDXINF;
            bool ok = false;
            if (j < Mloose) {
                int n = ident ? j : (int)cn[q][j];
                double dx = (double)xb[n * 3 + 0] - cx;
                double dy = (double)xb[n * 3 + 1] - cy;
                double dz = (double)xb[n * 3 + 2] - cz;
                double x = dx * r00 + dy * r10 + dz * r20;
                double y = dx * r01 + dy * r11 + dz * r21;
                double z = dx * r02 + dy * r12 + dz * r22;
                double r2 = y * y + z * z;
                if (x >= hmin && x <= hmax && r2 < rad2) { ok = true; ck = r2; cnn = n; }
            }
            msum += __popcll(__ballot(ok));
            wave_sort64(ck, cnn, lane, false);          // chunk descending
            if ((ck < rk) || (ck == rk && cnn < rn)) { rk = ck; rn = cnn; }
            #pragma unroll
            for (int stride = 32; stride > 0; stride >>= 1)
                cmpx(rk, rn, lane, stride, true);       // clean -> ascending
        }
        if (lane == 0 && msum > 0) atomicAdd(&cnt2[q], msum);
        wr2[(wv << 6) + lane] = rk;
        wn [(wv << 6) + lane] = rn;
        __syncthreads();

        if (wv == 0) {
            const int Mtrue = cnt2[q];
            #pragma unroll
            for (int w = 1; w < 4; ++w) {
                int src = (w << 6) + (63 - lane);       // reversed -> desc
                double ck = wr2[src]; int cnn = wn[src];
                if ((ck < rk) || (ck == rk && cnn < rn)) { rk = ck; rn = cnn; }
                #pragma unroll
                for (int stride = 32; stride > 0; stride >>= 1)
                    cmpx(rk, rn, lane, stride, true);
            }
            int nsel  = min(Mtrue, S);
            int first = __shfl(rn, 0);
            int v = (lane < nsel) ? rn : ((nsel > 0) ? first : 0);
            if (lane < S) sel[lane] = v;
        }
        __syncthreads();

        // ---- grouped_xyz + sel store for this query ----
        if (tid < S) {
            int n = sel[tid];
            selw[(size_t)bp * S + tid] = (unsigned short)n;
            double dx = (double)xb[n * 3 + 0] - cx;
            double dy = (double)xb[n * 3 + 1] - cy;
            double dz = (double)xb[n * 3 + 2] - cz;
            float x = (float)(dx * r00 + dy * r10 + dz * r20);
            float y = (float)(dx * r01 + dy * r11 + dz * r21);
            float z = (float)(dx * r02 + dy * r12 + dz * r22);
            float* o = out + (((size_t)b * OC + 0) * P + p) * S + tid;
            o[0 * (size_t)P * S] = x;
            o[1 * (size_t)P * S] = y;
            o[2 * (size_t)P * S] = z;
        }
        __syncthreads();   // wr2/wn/sel reused next q
    }
}

// ---- Kernel 2: transposed feature gather, one feat row per block ----
// (R16/R17-verified) grid 512, block 1024: 16 independent gathers/thread,
// nontemporal output stores.
__global__ __launch_bounds__(1024, 8) void gather_kernel(
    const float* __restrict__ feat,           // (B, C, N)
    const unsigned short* __restrict__ selw,  // (B*P, 32)
    float* __restrict__ out)                  // (B, 3+C, P, S)
{
    const int N = 16384, P = 1024, C = 64, S = 32, OC = 67;
    const int bid  = blockIdx.x;
    const int c    = bid & 63;
    const int half = (bid >> 6) & 1;
    const int b    = bid >> 7;
    const int tid  = threadIdx.x;

    __shared__ unsigned short st[512 * 32];   // 32 KB sel tile (512 queries)

    const uint4* sp = reinterpret_cast<const uint4*>(
        selw + ((size_t)b * P + half * 512) * S);
    uint4* dl = reinterpret_cast<uint4*>(st);
    dl[tid]        = sp[tid];                 // 2048 uint4 / 1024 thr
    dl[1024 + tid] = sp[1024 + tid];
    __syncthreads();

    const float* fr = feat + ((size_t)b * C + c) * N;
    float* ob = out + (((size_t)b * OC + 3 + c) * P + half * 512) * S;

    int   ix[16];
    float v [16];
    #pragma unroll
    for (int k = 0; k < 16; ++k)
        ix[k] = st[k * 1024 + tid];
    #pragma unroll
    for (int k = 0; k < 16; ++k)              // 16 outstanding global loads
        v[k] = fr[ix[k]];
    #pragma unroll
    for (int k = 0; k < 16; ++k)              // coalesced streaming stores
        __builtin_nontemporal_store(v[k], &ob[k * 1024 + tid]);
}

extern "C" void kernel_launch(void* const* d_in, const int* in_sizes, int n_in,
                              void* d_out, int out_size, void* d_ws, size_t ws_size,
                              hipStream_t stream) {
    const float* radius  = (const float*)d_in[0];
    const float* hmin    = (const float*)d_in[1];
    const float* hmax    = (const float*)d_in[2];
    // d_in[3] = nsample (int, fixed 32) — compile-time constant here
    const float* xyz     = (const float*)d_in[4];
    const float* new_xyz = (const float*)d_in[5];
    const float* rot     = (const float*)d_in[6];
    const float* feat    = (const float*)d_in[7];
    float* out = (float*)d_out;
    unsigned short* selw = (unsigned short*)d_ws;   // 4096*32*2 = 256 KB

    hipLaunchKernelGGL(select_kernel, dim3(1024), dim3(256), 0, stream,
                       radius, hmin, hmax, xyz, new_xyz, rot, out, selw);
    hipLaunchKernelGGL(gather_kernel, dim3(512), dim3(1024), 0, stream,
                       feat, selw, out);
}

// Round 19
// 120.527 us; speedup vs baseline: 1.0898x; 1.0898x over previous
//
#include <hip/hip_runtime.h>

#define CAP    4608        // loose-candidate capacity (R10-R17 verified: exact
                           // <= 4096, loose margins add <= ~3%). PLUS overflow
                           // -proof fallback: if count > CAP, phase 2 scans all
                           // N points (identity) - truncation is impossible.
#define BIGK   1.0e300
#define IDXINF 0x7fffffff

// one bitonic compare-exchange stage across the 64-lane wave,
// lexicographic key (k asc, n asc)
__device__ __forceinline__ void cmpx(double& k, int& n, int lane, int stride, bool up) {
    double ok = __shfl_xor(k, stride);
    int    on = __shfl_xor(n, stride);
    bool oLess = (ok < k) || (ok == k && on < n);
    bool lower = (lane & stride) == 0;
    bool takeOther = lower ? (up ? oLess : !oLess) : (up ? !oLess : oLess);
    if (takeOther) { k = ok; n = on; }
}

// full 64-element bitonic sort across the wave (asc==true -> ascending)
__device__ __forceinline__ void wave_sort64(double& k, int& n, int lane, bool asc) {
    #pragma unroll
    for (int size = 2; size < 64; size <<= 1) {
        bool up = asc ? ((lane & size) == 0) : ((lane & size) != 0);
        #pragma unroll
        for (int stride = size >> 1; stride > 0; stride >>= 1)
            cmpx(k, n, lane, stride, up);
    }
    #pragma unroll
    for (int stride = 32; stride > 0; stride >>= 1)   // final size-64 pass
        cmpx(k, n, lane, stride, asc);
}

// ---- Kernel 1: selection + grouped_xyz; sel indices -> d_ws (ushort) ----
// R19: phase-1 hot loop is BRANCHLESS - passes recorded in a per-lane 64-bit
// register mask (each lane owns exactly 64 points: bit = it*4+k), drained to
// the LDS candidate list once after the scan. Removes the exec-mask churn +
// ds_add_rtn wait from ~72% of sub-iterations (R18 post-mortem cost model).
__global__ __launch_bounds__(256, 8) void select_kernel(
    const float* __restrict__ radius_p,
    const float* __restrict__ hmin_p,
    const float* __restrict__ hmax_p,
    const float* __restrict__ xyz,      // (B, N, 3)
    const float* __restrict__ new_xyz,  // (B, P, 3)
    const float* __restrict__ rot,      // (B, P, 3, 3)
    float* __restrict__ out,            // (B, 3+C, P, S)
    unsigned short* __restrict__ selw)  // (B*P, 32)
{
    const int N = 16384, P = 1024, S = 32, OC = 67;
    const int bp  = blockIdx.x;
    const int b   = bp >> 10;          // P = 1024
    const int p   = bp & (P - 1);
    const int tid = threadIdx.x;
    const int lane = tid & 63;
    const int wv   = tid >> 6;

    __shared__ unsigned short cn[CAP]; // loose candidates (ushort: N fits 16b)
    __shared__ double wr2[256];        // per-wave sorted keys for the merge
    __shared__ int    wn[256];
    __shared__ int    cnt;             // loose count
    __shared__ int    cnt2;            // exact survivor count
    __shared__ int    sel[32];

    if (tid == 0) { cnt = 0; cnt2 = 0; }
    __syncthreads();

    const double radius = (double)radius_p[0];
    const double hmin   = (double)hmin_p[0];
    const double hmax   = (double)hmax_p[0];
    const double rad2   = radius * radius;

    const float* nx = new_xyz + (size_t)bp * 3;
    const double cx = nx[0], cy = nx[1], cz = nx[2];
    const float* rp = rot + (size_t)bp * 9;
    const double r00 = rp[0], r01 = rp[1], r02 = rp[2];
    const double r10 = rp[3], r11 = rp[4], r12 = rp[5];
    const double r20 = rp[6], r21 = rp[7], r22 = rp[8];

    // Projection-form f32 loose filter (R14-verified): abs err <= ~1e-5,
    // 50-100x under the 5e-4/1e-3 margins.
    const float r00f = (float)r00, r01f = (float)r01, r02f = (float)r02;
    const float r10f = (float)r10, r11f = (float)r11, r12f = (float)r12;
    const float r20f = (float)r20, r21f = (float)r21, r22f = (float)r22;
    const float cpxf = (float)(cx * r00 + cy * r10 + cz * r20);
    const float cpyf = (float)(cx * r01 + cy * r11 + cz * r21);
    const float cpzf = (float)(cx * r02 + cy * r12 + cz * r22);
    const float hminf = (float)hmin - 5.0e-4f;
    const float hmaxf = (float)hmax + 5.0e-4f;
    const float rad2f = (float)rad2 + 1.0e-3f;

    const float* xb = xyz + (size_t)b * N * 3;
    const float4* vp = reinterpret_cast<const float4*>(xb);

    // ---- Phase 1: branchless f32 loose scan -> per-lane register mask ----
    unsigned long long pmask = 0ULL;
    float4 a0 = vp[tid * 3 + 0], a1 = vp[tid * 3 + 1], a2 = vp[tid * 3 + 2];
    for (int it = 0; it < 16; ++it) {               // 16 * 1024 = N
        const float4* q = vp + ((it + 1) & 15) * 768 + tid * 3;
        float4 b0 = q[0], b1 = q[1], b2 = q[2];     // prefetch (issue-early)
        float px[4], py[4], pz[4];
        px[0]=a0.x; py[0]=a0.y; pz[0]=a0.z;
        px[1]=a0.w; py[1]=a1.x; pz[1]=a1.y;
        px[2]=a1.z; py[2]=a1.w; pz[2]=a2.x;
        px[3]=a2.y; py[3]=a2.z; pz[3]=a2.w;
        #pragma unroll
        for (int k = 0; k < 4; ++k) {
            float xf  = fmaf(px[k], r00f, fmaf(py[k], r10f, fmaf(pz[k], r20f, -cpxf)));
            float yf  = fmaf(px[k], r01f, fmaf(py[k], r11f, fmaf(pz[k], r21f, -cpyf)));
            float zf  = fmaf(px[k], r02f, fmaf(py[k], r12f, fmaf(pz[k], r22f, -cpzf)));
            float r2f = fmaf(yf, yf, zf * zf);
            bool pass = (xf >= hminf) & (xf <= hmaxf) & (r2f < rad2f);
            pmask |= (unsigned long long)pass << (it * 4 + k);   // branchless
        }
        a0 = b0; a1 = b1; a2 = b2;
    }

    // drain: convert register masks to the LDS candidate list (~1.3/lane avg)
    while (pmask) {
        int bit = __builtin_ctzll(pmask);
        pmask &= pmask - 1;
        int n = ((bit >> 2) << 10) + tid * 4 + (bit & 3);  // it*1024+tid*4+k
        int slot = atomicAdd(&cnt, 1);
        if (slot < CAP) cn[slot] = (unsigned short)n;
    }
    __syncthreads();

    // Overflow-proof: if loose set overflowed, scan ALL points in phase 2.
    int  Mloose = cnt;
    bool ident  = false;
    if (Mloose > CAP) { Mloose = N; ident = true; }

    // ---- Phase 2: exact f64 decision fused into chunk load + streaming
    //      bitonic top-64 per wave, then 4-way merge ----
    // Exact decision (same op order as verified R1-R17) once per candidate,
    // dense 64-wide chunks; rejects = BIGK sentinels; survivor count via
    // ballot popcount. Order-independent -> append order irrelevant.
    double rk = BIGK; int rn = IDXINF;
    int msum = 0;
    const int nch = (Mloose + 63) >> 6;
    for (int ch = wv; ch < nch; ch += 4) {
        int j = (ch << 6) + lane;
        double ck = BIGK; int cnn = IDXINF;
        bool ok = false;
        if (j < Mloose) {
            int n = ident ? j : (int)cn[j];
            double dx = (double)xb[n * 3 + 0] - cx;
            double dy = (double)xb[n * 3 + 1] - cy;
            double dz = (double)xb[n * 3 + 2] - cz;
            double x = dx * r00 + dy * r10 + dz * r20;
            double y = dx * r01 + dy * r11 + dz * r21;
            double z = dx * r02 + dy * r12 + dz * r22;
            double r2 = y * y + z * z;
            if (x >= hmin && x <= hmax && r2 < rad2) { ok = true; ck = r2; cnn = n; }
        }
        msum += __popcll(__ballot(ok));             // wave-uniform count
        wave_sort64(ck, cnn, lane, false);          // chunk descending
        if ((ck < rk) || (ck == rk && cnn < rn)) { rk = ck; rn = cnn; }  // keep 64 smallest
        #pragma unroll
        for (int stride = 32; stride > 0; stride >>= 1)  // bitonic clean -> ascending
            cmpx(rk, rn, lane, stride, true);
    }
    if (lane == 0 && msum > 0) atomicAdd(&cnt2, msum);
    // park each wave's sorted list for the cross-wave merge
    wr2[(wv << 6) + lane] = rk;
    wn [(wv << 6) + lane] = rn;
    __syncthreads();

    if (wv == 0) {
        const int Mtrue = cnt2;
        #pragma unroll
        for (int w = 1; w < 4; ++w) {
            int src = (w << 6) + (63 - lane);       // reversed -> descending
            double ck = wr2[src]; int cnn = wn[src];
            if ((ck < rk) || (ck == rk && cnn < rn)) { rk = ck; rn = cnn; }
            #pragma unroll
            for (int stride = 32; stride > 0; stride >>= 1)
                cmpx(rk, rn, lane, stride, true);
        }
        // lanes 0..31 now hold the exact top-32 in ascending (r2, idx) order
        int nsel  = min(Mtrue, S);
        int first = __shfl(rn, 0);
        int v = (lane < nsel) ? rn : ((nsel > 0) ? first : 0);
        if (lane < S) sel[lane] = v;
    }
    __syncthreads();

    // ---- grouped_xyz + sel store ----
    if (tid < S) {
        int n = sel[tid];
        selw[(size_t)bp * S + tid] = (unsigned short)n;
        double dx = (double)xb[n * 3 + 0] - cx;
        double dy = (double)xb[n * 3 + 1] - cy;
        double dz = (double)xb[n * 3 + 2] - cz;
        float x = (float)(dx * r00 + dy * r10 + dz * r20);
        float y = (float)(dx * r01 + dy * r11 + dz * r21);
        float z = (float)(dx * r02 + dy * r12 + dz * r22);
        float* o = out + (((size_t)b * OC + 0) * P + p) * S + tid;
        o[0 * (size_t)P * S] = x;
        o[1 * (size_t)P * S] = y;
        o[2 * (size_t)P * S] = z;
    }
}

// ---- Kernel 2: transposed feature gather, one feat row per block ----
// (R16/R17-verified) grid 512, block 1024: 16 independent gathers/thread,
// nontemporal output stores.
__global__ __launch_bounds__(1024, 8) void gather_kernel(
    const float* __restrict__ feat,           // (B, C, N)
    const unsigned short* __restrict__ selw,  // (B*P, 32)
    float* __restrict__ out)                  // (B, 3+C, P, S)
{
    const int N = 16384, P = 1024, C = 64, S = 32, OC = 67;
    const int bid  = blockIdx.x;
    const int c    = bid & 63;
    const int half = (bid >> 6) & 1;
    const int b    = bid >> 7;
    const int tid  = threadIdx.x;

    __shared__ unsigned short st[512 * 32];   // 32 KB sel tile (512 queries)

    const uint4* sp = reinterpret_cast<const uint4*>(
        selw + ((size_t)b * P + half * 512) * S);
    uint4* dl = reinterpret_cast<uint4*>(st);
    dl[tid]        = sp[tid];                 // 2048 uint4 / 1024 thr
    dl[1024 + tid] = sp[1024 + tid];
    __syncthreads();

    const float* fr = feat + ((size_t)b * C + c) * N;
    float* ob = out + (((size_t)b * OC + 3 + c) * P + half * 512) * S;

    int   ix[16];
    float v [16];
    #pragma unroll
    for (int k = 0; k < 16; ++k)
        ix[k] = st[k * 1024 + tid];
    #pragma unroll
    for (int k = 0; k < 16; ++k)              // 16 outstanding global loads
        v[k] = fr[ix[k]];
    #pragma unroll
    for (int k = 0; k < 16; ++k)              // coalesced streaming stores
        __builtin_nontemporal_store(v[k], &ob[k * 1024 + tid]);
}

extern "C" void kernel_launch(void* const* d_in, const int* in_sizes, int n_in,
                              void* d_out, int out_size, void* d_ws, size_t ws_size,
                              hipStream_t stream) {
    const float* radius  = (const float*)d_in[0];
    const float* hmin    = (const float*)d_in[1];
    const float* hmax    = (const float*)d_in[2];
    // d_in[3] = nsample (int, fixed 32) — compile-time constant here
    const float* xyz     = (const float*)d_in[4];
    const float* new_xyz = (const float*)d_in[5];
    const float* rot     = (const float*)d_in[6];
    const float* feat    = (const float*)d_in[7];
    float* out = (float*)d_out;
    unsigned short* selw = (unsigned short*)d_ws;   // 4096*32*2 = 256 KB

    hipLaunchKernelGGL(select_kernel, dim3(4096), dim3(256), 0, stream,
                       radius, hmin, hmax, xyz, new_xyz, rot, out, selw);
    hipLaunchKernelGGL(gather_kernel, dim3(512), dim3(1024), 0, stream,
                       feat, selw, out);
}

// Round 20
// 108.676 us; speedup vs baseline: 1.2086x; 1.1090x over previous
//
#include <hip/hip_runtime.h>

#define CAP    4608        // loose-candidate capacity (R10-R15 verified: exact
                           // <= 4096, loose margins add <= ~3%). PLUS overflow
                           // -proof fallback: if count > CAP, phase 2 scans all
                           // N points (identity) - truncation is impossible.
#define BIGK   1.0e300
#define IDXINF 0x7fffffff

// one bitonic compare-exchange stage across the 64-lane wave,
// lexicographic key (k asc, n asc)
__device__ __forceinline__ void cmpx(double& k, int& n, int lane, int stride, bool up) {
    double ok = __shfl_xor(k, stride);
    int    on = __shfl_xor(n, stride);
    bool oLess = (ok < k) || (ok == k && on < n);
    bool lower = (lane & stride) == 0;
    bool takeOther = lower ? (up ? oLess : !oLess) : (up ? !oLess : oLess);
    if (takeOther) { k = ok; n = on; }
}

// full 64-element bitonic sort across the wave (asc==true -> ascending)
__device__ __forceinline__ void wave_sort64(double& k, int& n, int lane, bool asc) {
    #pragma unroll
    for (int size = 2; size < 64; size <<= 1) {
        bool up = asc ? ((lane & size) == 0) : ((lane & size) != 0);
        #pragma unroll
        for (int stride = size >> 1; stride > 0; stride >>= 1)
            cmpx(k, n, lane, stride, up);
    }
    #pragma unroll
    for (int stride = 32; stride > 0; stride >>= 1)   // final size-64 pass
        cmpx(k, n, lane, stride, asc);
}

// ---- Kernel 1: selection + grouped_xyz; sel indices -> d_ws (ushort) ----
// LOCKED CONFIG (R17-verified 90.4 us). Lessons encoded:
//  - per-lane atomicAdd append: compiler wave-coalesces it; manual ballot
//    (R16, +13us), register-mask drain (R19, +14us), and multi-query sharing
//    (R18, +20us) all regressed. Do not restructure phase 1.
//  - f64 selection keys are mandatory: f32-indistinguishable r2 pairs are
//    statistically guaranteed at this scale; a top-32 rank swap = O(1) error.
__global__ __launch_bounds__(256, 8) void select_kernel(
    const float* __restrict__ radius_p,
    const float* __restrict__ hmin_p,
    const float* __restrict__ hmax_p,
    const float* __restrict__ xyz,      // (B, N, 3)
    const float* __restrict__ new_xyz,  // (B, P, 3)
    const float* __restrict__ rot,      // (B, P, 3, 3)
    float* __restrict__ out,            // (B, 3+C, P, S)
    unsigned short* __restrict__ selw)  // (B*P, 32)
{
    const int N = 16384, P = 1024, S = 32, OC = 67;
    const int bp  = blockIdx.x;
    const int b   = bp >> 10;          // P = 1024
    const int p   = bp & (P - 1);
    const int tid = threadIdx.x;
    const int lane = tid & 63;
    const int wv   = tid >> 6;

    __shared__ unsigned short cn[CAP]; // loose candidates (ushort: N fits 16b)
    __shared__ double wr2[256];        // per-wave sorted keys for the merge
    __shared__ int    wn[256];
    __shared__ int    cnt;             // loose count
    __shared__ int    cnt2;            // exact survivor count
    __shared__ int    sel[32];

    if (tid == 0) { cnt = 0; cnt2 = 0; }
    __syncthreads();

    const double radius = (double)radius_p[0];
    const double hmin   = (double)hmin_p[0];
    const double hmax   = (double)hmax_p[0];
    const double rad2   = radius * radius;

    const float* nx = new_xyz + (size_t)bp * 3;
    const double cx = nx[0], cy = nx[1], cz = nx[2];
    const float* rp = rot + (size_t)bp * 9;
    const double r00 = rp[0], r01 = rp[1], r02 = rp[2];
    const double r10 = rp[3], r11 = rp[4], r12 = rp[5];
    const double r20 = rp[6], r21 = rp[7], r22 = rp[8];

    // Projection-form f32 loose filter: local_d = P.u_d - cp_d where
    // cp_d = c.u_d is folded into one constant per output dim -> no per-point
    // subtractions. Error: abs err <= ~1e-5, 50-100x under the margins.
    const float r00f = (float)r00, r01f = (float)r01, r02f = (float)r02;
    const float r10f = (float)r10, r11f = (float)r11, r12f = (float)r12;
    const float r20f = (float)r20, r21f = (float)r21, r22f = (float)r22;
    const float cpxf = (float)(cx * r00 + cy * r10 + cz * r20);
    const float cpyf = (float)(cx * r01 + cy * r11 + cz * r21);
    const float cpzf = (float)(cx * r02 + cy * r12 + cz * r22);
    const float hminf = (float)hmin - 5.0e-4f;
    const float hmaxf = (float)hmax + 5.0e-4f;
    const float rad2f = (float)rad2 + 1.0e-3f;

    const float* xb = xyz + (size_t)b * N * 3;
    const float4* vp = reinterpret_cast<const float4*>(xb);

    // ---- Phase 1: pure-f32 loose scan, software-pipelined loads ----
    float4 a0 = vp[tid * 3 + 0], a1 = vp[tid * 3 + 1], a2 = vp[tid * 3 + 2];
    for (int it = 0; it < 16; ++it) {               // 16 * 1024 = N
        const float4* q = vp + ((it + 1) & 15) * 768 + tid * 3;
        float4 b0 = q[0], b1 = q[1], b2 = q[2];     // prefetch (issue-early)
        int g = it * 1024 + tid * 4;
        float px[4], py[4], pz[4];
        px[0]=a0.x; py[0]=a0.y; pz[0]=a0.z;
        px[1]=a0.w; py[1]=a1.x; pz[1]=a1.y;
        px[2]=a1.z; py[2]=a1.w; pz[2]=a2.x;
        px[3]=a2.y; py[3]=a2.z; pz[3]=a2.w;
        #pragma unroll
        for (int k = 0; k < 4; ++k) {
            float xf  = fmaf(px[k], r00f, fmaf(py[k], r10f, fmaf(pz[k], r20f, -cpxf)));
            float yf  = fmaf(px[k], r01f, fmaf(py[k], r11f, fmaf(pz[k], r21f, -cpyf)));
            float zf  = fmaf(px[k], r02f, fmaf(py[k], r12f, fmaf(pz[k], r22f, -cpzf)));
            float r2f = fmaf(yf, yf, zf * zf);
            if (xf >= hminf && xf <= hmaxf && r2f < rad2f) {
                int slot = atomicAdd(&cnt, 1);
                if (slot < CAP) cn[slot] = (unsigned short)(g + k);
            }
        }
        a0 = b0; a1 = b1; a2 = b2;
    }
    __syncthreads();

    // Overflow-proof: if loose set overflowed, scan ALL points in phase 2.
    int  Mloose = cnt;
    bool ident  = false;
    if (Mloose > CAP) { Mloose = N; ident = true; }

    // ---- Phase 2: exact f64 decision fused into chunk load + streaming
    //      bitonic top-64 per wave, then 4-way merge ----
    // Exact decision (same op order as verified R1-R17) once per candidate,
    // dense 64-wide chunks; rejects = BIGK sentinels; survivor count via
    // ballot popcount.
    double rk = BIGK; int rn = IDXINF;
    int msum = 0;
    const int nch = (Mloose + 63) >> 6;
    for (int ch = wv; ch < nch; ch += 4) {
        int j = (ch << 6) + lane;
        double ck = BIGK; int cnn = IDXINF;
        bool ok = false;
        if (j < Mloose) {
            int n = ident ? j : (int)cn[j];
            double dx = (double)xb[n * 3 + 0] - cx;
            double dy = (double)xb[n * 3 + 1] - cy;
            double dz = (double)xb[n * 3 + 2] - cz;
            double x = dx * r00 + dy * r10 + dz * r20;
            double y = dx * r01 + dy * r11 + dz * r21;
            double z = dx * r02 + dy * r12 + dz * r22;
            double r2 = y * y + z * z;
            if (x >= hmin && x <= hmax && r2 < rad2) { ok = true; ck = r2; cnn = n; }
        }
        msum += __popcll(__ballot(ok));             // wave-uniform count
        wave_sort64(ck, cnn, lane, false);          // chunk descending
        if ((ck < rk) || (ck == rk && cnn < rn)) { rk = ck; rn = cnn; }  // keep 64 smallest
        #pragma unroll
        for (int stride = 32; stride > 0; stride >>= 1)  // bitonic clean -> ascending
            cmpx(rk, rn, lane, stride, true);
    }
    if (lane == 0 && msum > 0) atomicAdd(&cnt2, msum);
    // park each wave's sorted list for the cross-wave merge
    wr2[(wv << 6) + lane] = rk;
    wn [(wv << 6) + lane] = rn;
    __syncthreads();

    if (wv == 0) {
        const int Mtrue = cnt2;
        #pragma unroll
        for (int w = 1; w < 4; ++w) {
            int src = (w << 6) + (63 - lane);       // reversed -> descending
            double ck = wr2[src]; int cnn = wn[src];
            if ((ck < rk) || (ck == rk && cnn < rn)) { rk = ck; rn = cnn; }
            #pragma unroll
            for (int stride = 32; stride > 0; stride >>= 1)
                cmpx(rk, rn, lane, stride, true);
        }
        // lanes 0..31 now hold the exact top-32 in ascending (r2, idx) order
        int nsel  = min(Mtrue, S);
        int first = __shfl(rn, 0);
        int v = (lane < nsel) ? rn : ((nsel > 0) ? first : 0);
        if (lane < S) sel[lane] = v;
    }
    __syncthreads();

    // ---- grouped_xyz + sel store ----
    if (tid < S) {
        int n = sel[tid];
        selw[(size_t)bp * S + tid] = (unsigned short)n;
        double dx = (double)xb[n * 3 + 0] - cx;
        double dy = (double)xb[n * 3 + 1] - cy;
        double dz = (double)xb[n * 3 + 2] - cz;
        float x = (float)(dx * r00 + dy * r10 + dz * r20);
        float y = (float)(dx * r01 + dy * r11 + dz * r21);
        float z = (float)(dx * r02 + dy * r12 + dz * r22);
        float* o = out + (((size_t)b * OC + 0) * P + p) * S + tid;
        o[0 * (size_t)P * S] = x;
        o[1 * (size_t)P * S] = y;
        o[2 * (size_t)P * S] = z;
    }
}

// ---- Kernel 2: transposed feature gather, one feat row per block ----
// (R16/R17-verified fast version) grid 512, block 1024: c = bid & 63,
// half = (bid>>6) & 1, b = bid >> 7. Each thread: 16 INDEPENDENT gathers
// (load-all-then-store-all -> 16 outstanding loads of memory-level
// parallelism). Nontemporal stores keep the 33.5 MB output stream from
// evicting the L2-hot feat rows.
__global__ __launch_bounds__(1024, 8) void gather_kernel(
    const float* __restrict__ feat,           // (B, C, N)
    const unsigned short* __restrict__ selw,  // (B*P, 32)
    float* __restrict__ out)                  // (B, 3+C, P, S)
{
    const int N = 16384, P = 1024, C = 64, S = 32, OC = 67;
    const int bid  = blockIdx.x;
    const int c    = bid & 63;
    const int half = (bid >> 6) & 1;
    const int b    = bid >> 7;
    const int tid  = threadIdx.x;

    __shared__ unsigned short st[512 * 32];   // 32 KB sel tile (512 queries)

    const uint4* sp = reinterpret_cast<const uint4*>(
        selw + ((size_t)b * P + half * 512) * S);
    uint4* dl = reinterpret_cast<uint4*>(st);
    dl[tid]        = sp[tid];                 // 2048 uint4 / 1024 thr
    dl[1024 + tid] = sp[1024 + tid];
    __syncthreads();

    const float* fr = feat + ((size_t)b * C + c) * N;
    float* ob = out + (((size_t)b * OC + 3 + c) * P + half * 512) * S;

    int   ix[16];
    float v [16];
    #pragma unroll
    for (int k = 0; k < 16; ++k)              // LDS reads (cheap)
        ix[k] = st[k * 1024 + tid];
    #pragma unroll
    for (int k = 0; k < 16; ++k)              // 16 outstanding global loads
        v[k] = fr[ix[k]];
    #pragma unroll
    for (int k = 0; k < 16; ++k)              // coalesced streaming stores
        __builtin_nontemporal_store(v[k], &ob[k * 1024 + tid]);
}

extern "C" void kernel_launch(void* const* d_in, const int* in_sizes, int n_in,
                              void* d_out, int out_size, void* d_ws, size_t ws_size,
                              hipStream_t stream) {
    const float* radius  = (const float*)d_in[0];
    const float* hmin    = (const float*)d_in[1];
    const float* hmax    = (const float*)d_in[2];
    // d_in[3] = nsample (int, fixed 32) — compile-time constant here
    const float* xyz     = (const float*)d_in[4];
    const float* new_xyz = (const float*)d_in[5];
    const float* rot     = (const float*)d_in[6];
    const float* feat    = (const float*)d_in[7];
    float* out = (float*)d_out;
    unsigned short* selw = (unsigned short*)d_ws;   // 4096*32*2 = 256 KB

    hipLaunchKernelGGL(select_kernel, dim3(4096), dim3(256), 0, stream,
                       radius, hmin, hmax, xyz, new_xyz, rot, out, selw);
    hipLaunchKernelGGL(gather_kernel, dim3(512), dim3(1024), 0, stream,
                       feat, selw, out);
}